// Round 4
// baseline (268.206 us; speedup 1.0000x reference)
//
#include <hip/hip_runtime.h>
#include <hip/hip_bf16.h>

// BinaryLinear: out[131072,256] = x[131072,256] @ (sign(W)*scale)[256,256]^T + bias
// Strategy: bf16 MFMA (16x16x32), sign(W) as exact bf16 +-1, scale/bias in f32 epilogue.
// Memory-bound: 268 MB traffic -> ~43 us floor at 6.3 TB/s.

typedef __bf16 bf16_t;
typedef __attribute__((ext_vector_type(8))) __bf16 bf16x8;  // MFMA A/B fragment (4 VGPR)
typedef __attribute__((ext_vector_type(4))) float f32x4;    // MFMA C/D fragment
typedef __attribute__((ext_vector_type(4))) short s16x4;    // 8-byte LDS write chunk

#define MROWS 131072
#define NDIM 256
#define KDIM 256
#define BM 64

// ---- Kernel 1: wb[o][i] = bf16(sign(W[o][i]))  (+1/-1/0, exact in bf16) ----
__global__ __launch_bounds__(256) void prep_w_kernel(const float* __restrict__ W,
                                                     bf16_t* __restrict__ wb) {
    int idx = blockIdx.x * 256 + threadIdx.x;   // 0 .. 65535
    float w = W[idx];
    float v = (w > 0.0f) ? 1.0f : ((w < 0.0f) ? -1.0f : 0.0f);
    wb[idx] = (bf16_t)v;
}

// ---- Kernel 2: the GEMM ----
// Workgroup: 256 threads (4 waves). Tile: BM=64 rows x full N=256 x full K=256.
// A (x) staged in LDS as bf16 with XOR swizzle; B (wb) read from global (L2-resident).
__global__ __launch_bounds__(256) void bin_gemm_kernel(
        const float* __restrict__ x,
        const bf16_t* __restrict__ wb,
        const float* __restrict__ scale,
        const float* __restrict__ bias,
        float* __restrict__ out) {
    // 64 rows x 256 bf16 = 32 KiB, row stride 512 B, XOR-swizzled (T2 pattern).
    __shared__ __align__(16) char Alds[BM * KDIM * 2];

    const int tid   = threadIdx.x;
    const int lane  = tid & 63;
    const int wave  = tid >> 6;
    const int mbase = blockIdx.x * BM;

    // ---- stage x tile: 64x256 f32 is one contiguous 64 KiB block (full-K tile) ----
    const float* xt = x + (size_t)mbase * KDIM;
    #pragma unroll
    for (int i = 0; i < 16; ++i) {
        int q    = i * 256 + tid;    // float4 index within tile, 0..4095
        int row  = q >> 6;           // 64 float4 per 256-float row
        int colq = q & 63;
        f32x4 v = *reinterpret_cast<const f32x4*>(xt + (size_t)q * 4);
        bf16_t b0 = (bf16_t)v.x, b1 = (bf16_t)v.y, b2 = (bf16_t)v.z, b3 = (bf16_t)v.w;
        s16x4 b;
        b.x = *reinterpret_cast<short*>(&b0);
        b.y = *reinterpret_cast<short*>(&b1);
        b.z = *reinterpret_cast<short*>(&b2);
        b.w = *reinterpret_cast<short*>(&b3);
        int boff = row * 512 + ((colq * 8) ^ ((row & 7) << 4));  // swizzled byte offset
        *reinterpret_cast<s16x4*>(Alds + boff) = b;
    }
    __syncthreads();

    const int obase = wave * 64;   // each wave owns 64 output cols, all 64 rows
    const int lrow  = lane & 15;
    const int lk    = lane >> 4;

    f32x4 acc[4][4] = {};          // 4 m-frags x 4 n-frags of 16x16

    #pragma unroll
    for (int ks = 0; ks < 8; ++ks) {           // K = 8 x 32
        bf16x8 a[4], b[4];
        #pragma unroll
        for (int mi = 0; mi < 4; ++mi) {
            int row  = mi * 16 + lrow;
            int cb   = ks * 64 + lk * 16;      // byte col within row
            int boff = row * 512 + (cb ^ ((row & 7) << 4));
            a[mi] = *reinterpret_cast<const bf16x8*>(Alds + boff);
        }
        #pragma unroll
        for (int ni = 0; ni < 4; ++ni) {
            int orow = obase + ni * 16 + lrow;
            const bf16_t* p = wb + (size_t)orow * KDIM + ks * 32 + lk * 8;
            b[ni] = *reinterpret_cast<const bf16x8*>(p);   // global_load_dwordx4, L2-hit
        }
        #pragma unroll
        for (int mi = 0; mi < 4; ++mi)
            #pragma unroll
            for (int ni = 0; ni < 4; ++ni)
                acc[mi][ni] = __builtin_amdgcn_mfma_f32_16x16x32_bf16(
                                  a[mi], b[ni], acc[mi][ni], 0, 0, 0);
    }

    // ---- epilogue: out = acc * scale[col] + bias[col] (f32) ----
    float sc[4], bi[4];
    #pragma unroll
    for (int ni = 0; ni < 4; ++ni) {
        int col = obase + ni * 16 + lrow;
        sc[ni] = scale[col];
        bi[ni] = bias[col];
    }
    #pragma unroll
    for (int mi = 0; mi < 4; ++mi) {
        #pragma unroll
        for (int ni = 0; ni < 4; ++ni) {
            int col = obase + ni * 16 + lrow;
            #pragma unroll
            for (int r = 0; r < 4; ++r) {
                int row = mbase + mi * 16 + lk * 4 + r;   // C/D: row=(lane>>4)*4+r, col=lane&15
                out[(size_t)row * NDIM + col] = acc[mi][ni][r] * sc[ni] + bi[ni];
            }
        }
    }
}

extern "C" void kernel_launch(void* const* d_in, const int* in_sizes, int n_in,
                              void* d_out, int out_size, void* d_ws, size_t ws_size,
                              hipStream_t stream) {
    const float* x     = (const float*)d_in[0];
    const float* W     = (const float*)d_in[1];
    const float* scale = (const float*)d_in[2];
    const float* bias  = (const float*)d_in[3];
    float*       out   = (float*)d_out;
    bf16_t*      wb    = (bf16_t*)d_ws;        // 256*256*2 = 128 KiB scratch

    prep_w_kernel<<<NDIM * KDIM / 256, 256, 0, stream>>>(W, wb);
    bin_gemm_kernel<<<MROWS / BM, 256, 0, stream>>>(x, wb, scale, bias, out);
}